// Round 4
// baseline (1345.530 us; speedup 1.0000x reference)
//
#include <hip/hip_runtime.h>
#include <hip/hip_bf16.h>
#include <hip/hip_cooperative_groups.h>

namespace cg = cooperative_groups;

// B=8, N=4096, D=1024, 3 iterations.
// r9: persistent kernel via hipLaunchCooperativeKernel (guide-sanctioned,
// fail-fast) instead of r8's hand-rolled barrier (hang risk). r5 algebra
// (chained 8-row GEMVs; the r6/r7 Q=Wf@M^T precompute was a bad trade):
//   t = qLN @ M ; v = t @ Wf^T ; delta[b,n] = feat[b,n,:].v
//   s = c @ feat ; u = s @ Wf ; out = u @ M^T
// All iteration phases inside ONE cooperative kernel (512 blk x 256 thr,
// __launch_bounds__(256,2) -> <=128 VGPR -> 2 blocks/CU), separated by
// grid.sync(). ph_feat restored to r5's low-register body (no dp[16]/cc16[16]
// arrays) so the 128-VGPR cap does not spill the hot loop.
// If cooperative launch errors, a discrete-kernel fallback sequence (same
// phase helpers, ~26 launches ~= r5's 430us) runs instead.
// Launches: kdet + kprep + kcoop = 3.
// Harness poisons a 512 MiB workspace (~78 us/call, fillBufferAligned) —
// unavoidable kernel-side.

using u16 = unsigned short;
using u32 = unsigned int;
using u8  = unsigned char;
using u64 = unsigned long long;

#define SELU_L 1.0507009873554805f
#define SELU_A 1.6732632423543772f

__device__ float g_M[1048576];   // Wg mean (fp32), [d][j]
__device__ float g_q[8192];      // q0 (zeroed by kdet, filled via kprep atomics)
__device__ float g_qc[8192];     // current LN'd q state
__device__ float g_t[8192];      // t = qc @ M
__device__ float g_u[8192];      // u = s @ Wf
__device__ float g_s[8192];      // s = c @ feat
__device__ float g_bst[32768];   // b logits state
__device__ float g_c[32768];     // softmax
__device__ float g_delta[32768];
__device__ float g_outv[8192];
__device__ float g_v[8192];
__device__ int   g_dt[12];       // 0..8: 0=bf16,1=f32 per float input; [9]=mask mode

constexpr int NBLK = 512;

__device__ __forceinline__ float blo(u32 u){ return __uint_as_float(u << 16); }
__device__ __forceinline__ float bhi(u32 u){ return __uint_as_float(u & 0xffff0000u); }
__device__ __forceinline__ float b2f(u16 u){ return __uint_as_float(((u32)u) << 16); }

__device__ __forceinline__ void unpack8(uint4 x, float* f){
  f[0]=blo(x.x); f[1]=bhi(x.x); f[2]=blo(x.y); f[3]=bhi(x.y);
  f[4]=blo(x.z); f[5]=bhi(x.z); f[6]=blo(x.w); f[7]=bhi(x.w);
}

__device__ __forceinline__ float ldf(const void* p, size_t i, int dt){
  return dt ? ((const float*)p)[i] : b2f(((const u16*)p)[i]);
}
__device__ __forceinline__ void load8(const void* base, size_t idx, int dt, float* f){
  if (dt == 0) {
    uint4 x = *(const uint4*)((const u16*)base + idx);
    unpack8(x, f);
  } else {
    const float* p = (const float*)base + idx;
    float4 a = *(const float4*)p, b = *(const float4*)(p + 4);
    f[0]=a.x; f[1]=a.y; f[2]=a.z; f[3]=a.w; f[4]=b.x; f[5]=b.y; f[6]=b.z; f[7]=b.w;
  }
}

__device__ __forceinline__ float wredsum(float x){
#pragma unroll
  for (int o = 32; o; o >>= 1) x += __shfl_xor(x, o, 64);
  return x;
}

// ---- dtype sniffer (wave-parallel) + zero g_q -------------------------------
__global__ void kdet(const void* p0, const void* p1, const void* p2, const void* p3,
                     const void* p4, const void* p5, const void* p6, const void* p7,
                     const void* p8, const void* p9)
{
  const void* ps[10] = {p0,p1,p2,p3,p4,p5,p6,p7,p8,p9};
  int tid = threadIdx.x;
  int w = tid >> 6, lane = tid & 63;
  if (w < 9) {
    const u16* wp = (const u16*)ps[w];
    u16 x0 = wp[lane], x1 = wp[64 + lane];
    int e0 = (x0 >> 7) & 0xFF, e1 = (x1 >> 7) & 0xFF;
    u64 nz0 = __ballot(x0 != 0), nz1 = __ballot(x1 != 0);
    u64 pa0 = __ballot(x0 != 0 && e0 >= 0x70 && e0 <= 0x8F);
    u64 pa1 = __ballot(x1 != 0 && e1 >= 0x70 && e1 <= 0x8F);
    if (lane == 0) {
      const u64 evenm = 0x5555555555555555ULL;   // i parity == lane parity
      int nz = __popcll(nz0) + __popcll(nz1);
      int pass = __popcll(pa0) + __popcll(pa1);
      int evenNZ = __popcll(nz0 & evenm) + __popcll(nz1 & evenm);
      int oddNZ  = nz - evenNZ;
      int dt;
      if (nz == 0)                    dt = 0;
      else if (evenNZ == 0 && oddNZ)  dt = 1;    // f32 signature
      else                            dt = (pass * 10 >= nz * 9) ? 0 : 1;
      g_dt[w] = dt;
    }
  } else if (w == 9) {
    const u8* mp = (const u8*)ps[9];
    u64 v = ((const u64*)mp)[lane];              // bytes lane*8 .. lane*8+7
    bool f16c=false, isF=false, nz01=false, nzNon4=false, nzM8_4=false, anynz=false;
#pragma unroll
    for (int j = 0; j < 8; ++j) {
      u8 cb = (u8)(v >> (8 * j));
      if (!cb) continue;
      int i = lane * 8 + j;
      anynz = true;
      if (cb == 0x3C && (i & 1)) f16c = true;
      if (cb == 0x3F || cb == 0x80) isF = true;
      int m = i & 3;
      if (m == 0 || m == 1) nz01 = true;
      if (m != 0) nzNon4 = true;
      if ((i & 7) == 4) nzM8_4 = true;
    }
    bool A  = __ballot(f16c)   != 0;
    bool Bf = __ballot(isF)    != 0;
    bool C  = __ballot(nz01)   != 0;
    bool Dn = __ballot(nzNon4) != 0;
    bool E  = __ballot(nzM8_4) != 0;
    bool F  = __ballot(anynz)  != 0;
    if (lane == 0) {
      int mode;
      if (A)       mode = 4;                     // f16
      else if (Bf) mode = C ? 2 : 3;             // bf16 : f32
      else if (Dn) mode = 0;                     // u8
      else if (E)  mode = 1;                     // i32
      else if (F)  mode = 5;                     // i64
      else         mode = 1;
      g_dt[9] = mode;
    }
  }
  for (int i = tid; i < 8192; i += 640) g_q[i] = 0.f;
}

// ---- prep: M (<1024) | q0 split-64 (<1088) | mask (<1120) -------------------
__global__ void kprep(const void* __restrict__ Wg, const void* __restrict__ Wh,
                      const void* __restrict__ query, const u8* __restrict__ maskp)
{
  int blk = blockIdx.x, tid = threadIdx.x;
  if (blk < 1024) {
    int dtg = g_dt[4];
    int e = blk * 1024 + tid * 4;
    float a0=0.f,a1=0.f,a2=0.f,a3=0.f;
#pragma unroll
    for (int g = 0; g < 4; ++g) {
      size_t o = (size_t)g * 1048576 + e;
      a0 += ldf(Wg, o+0, dtg); a1 += ldf(Wg, o+1, dtg);
      a2 += ldf(Wg, o+2, dtg); a3 += ldf(Wg, o+3, dtg);
    }
    *(float4*)(g_M + e) = make_float4(a0*0.25f, a1*0.25f, a2*0.25f, a3*0.25f);
  } else if (blk < 1088) {
    // q0[b,k] += sum_{d in chunk} query[b,d] * Wh[d,k]; 4 k-tiles x 16 d-chunks
    int dtq = g_dt[0], dth = g_dt[2];
    __shared__ float ql[512];                    // [b][64]
    int blk2 = blk - 1024;
    int kt = blk2 & 3, dc = blk2 >> 2;
    for (int idx = tid; idx < 512; idx += 256) {
      int b = idx >> 6, d = idx & 63;
      ql[idx] = ldf(query, b * 1024 + dc * 64 + d, dtq);
    }
    __syncthreads();
    int k = kt * 256 + tid;
    float acc[8] = {0,0,0,0,0,0,0,0};
    for (int dd = 0; dd < 64; ++dd) {
      int d = dc * 64 + dd;
      float w = ldf(Wh, (size_t)d * 1024 + k, dth);
#pragma unroll
      for (int b = 0; b < 8; ++b) acc[b] += ql[(b << 6) + dd] * w;
    }
#pragma unroll
    for (int b = 0; b < 8; ++b) atomicAdd(&g_q[b * 1024 + k], acc[b]);
  } else {
    int mode = g_dt[9];
    int e0 = (blk - 1088) * 1024 + tid * 4;
#pragma unroll
    for (int j = 0; j < 4; ++j) {
      int e = e0 + j;
      bool on;
      if (mode == 0)      on = maskp[e] != 0;
      else if (mode == 1) on = ((const int*)maskp)[e] != 0;
      else if (mode == 2) on = ((const u16*)maskp)[e] != 0;
      else if (mode == 3) on = ((const u32*)maskp)[e] != 0;
      else if (mode == 4) on = ((const u16*)maskp)[e] != 0;
      else                on = ((const u64*)maskp)[e] != 0ULL;
      g_bst[e] = on ? -1e18f : 0.f;
    }
  }
}

// ---- phase helpers ----------------------------------------------------------

__device__ __forceinline__ void ph_softmax(int b, float* sm)
{
  int tid = threadIdx.x;
  const float* row = g_bst + b * 4096;
  float mx = -3.4e38f;
  for (int i = tid; i < 4096; i += 256) mx = fmaxf(mx, row[i]);
  sm[tid] = mx; __syncthreads();
  for (int s2 = 128; s2; s2 >>= 1) { if (tid < s2) sm[tid] = fmaxf(sm[tid], sm[tid + s2]); __syncthreads(); }
  mx = sm[0]; __syncthreads();
  float sum = 0.f;
  for (int i = tid; i < 4096; i += 256) {
    float e = __expf(row[i] - mx);
    g_c[b * 4096 + i] = e; sum += e;
  }
  sm[tid] = sum; __syncthreads();
  for (int s2 = 128; s2; s2 >>= 1) { if (tid < s2) sm[tid] += sm[tid + s2]; __syncthreads(); }
  float inv = 1.f / sm[0];
  for (int i = tid; i < 4096; i += 256) g_c[b * 4096 + i] *= inv;
}

// q_new[b] = LN(qsrc[b] + selu(outv[b]*scale)) -> g_qc[b]   (one b per block)
__device__ __forceinline__ void ph_ln(int b, const float* qsrc, float scale,
                                      const void* lnw, const void* lnb, float* sm)
{
  int tid = threadIdx.x;
  int dtw = g_dt[5], dtb = g_dt[6];
  float x[4]; float sum = 0.f, sq = 0.f;
#pragma unroll
  for (int j = 0; j < 4; ++j) {
    int d = tid * 4 + j;
    float o = g_outv[b * 1024 + d] * scale;
    float se = (o > 0.f) ? SELU_L * o : SELU_L * SELU_A * expm1f(o);
    float val = qsrc[b * 1024 + d] + se;
    x[j] = val; sum += val; sq += val * val;
  }
  sm[tid] = sum; __syncthreads();
  for (int s2 = 128; s2; s2 >>= 1) { if (tid < s2) sm[tid] += sm[tid + s2]; __syncthreads(); }
  sum = sm[0]; __syncthreads();
  sm[tid] = sq; __syncthreads();
  for (int s2 = 128; s2; s2 >>= 1) { if (tid < s2) sm[tid] += sm[tid + s2]; __syncthreads(); }
  sq = sm[0]; __syncthreads();
  float mean = sum / 1024.f;
  float var = fmaxf(sq / 1024.f - mean * mean, 0.f);   // ddof=0
  float rstd = rsqrtf(var + 1e-5f);
#pragma unroll
  for (int j = 0; j < 4; ++j) {
    int d = tid * 4 + j;
    g_qc[b * 1024 + d] = (x[j] - mean) * rstd * ldf(lnw, d, dtw) + ldf(lnb, d, dtb);
  }
}

// phase A dispatcher: softmax | LN/copy | zero s,t,u
__device__ __forceinline__ void ph_A(int blk, int iter, const void* lnw,
                                     const void* lnb, float* shm)
{
  int tid = threadIdx.x;
  if (blk < 8) {
    ph_softmax(blk, shm);
  } else if (blk < 16) {
    int b = blk - 8;
    if (iter == 0) {
      for (int j = tid; j < 1024; j += 256) g_qc[b * 1024 + j] = g_q[b * 1024 + j];
    } else {
      ph_ln(b, g_qc, 1.f / 4096.f, lnw, lnb, shm);
    }
  } else if (blk < 24) {
    int b = blk - 16;
    *(float4*)(g_s + b * 1024 + tid * 4) = make_float4(0.f, 0.f, 0.f, 0.f);
  } else if (blk < 32) {
    int b = blk - 24;
    *(float4*)(g_t + b * 1024 + tid * 4) = make_float4(0.f, 0.f, 0.f, 0.f);
  } else if (blk < 40) {
    int b = blk - 32;
    *(float4*)(g_u + b * 1024 + tid * 4) = make_float4(0.f, 0.f, 0.f, 0.f);
  }
}

// t[b,j] += sum_{d in 16-chunk} qc[b,d] * M[d,j]   (256 blocks: 4 jt x 64 dc)
__device__ __forceinline__ void ph_t(int blk, float* shm)
{
  int tid = threadIdx.x;
  int jt = blk & 3, dc4 = blk >> 2;
  if (tid < 128) {
    int b = tid >> 4, dd = tid & 15;
    shm[tid] = g_qc[b * 1024 + dc4 * 16 + dd];
  }
  __syncthreads();
  int j = jt * 256 + tid;
  float acc[8] = {0,0,0,0,0,0,0,0};
  for (int dd = 0; dd < 16; ++dd) {
    float mv = g_M[(size_t)(dc4 * 16 + dd) * 1024 + j];
#pragma unroll
    for (int b = 0; b < 8; ++b) acc[b] += shm[(b << 4) + dd] * mv;
  }
#pragma unroll
  for (int b = 0; b < 8; ++b) atomicAdd(&g_t[b * 1024 + j], acc[b]);
  __syncthreads();
}

// v[b,k] = t[b,:] . Wf[k,:]   (256 blocks, wave per k row)
__device__ __forceinline__ void ph_v(int blk, const void* Wf, float* shm)
{
  int tid = threadIdx.x;
  int dtf = g_dt[3];
  for (int i = tid; i < 8192; i += 256) shm[i] = g_t[i];
  __syncthreads();
  int w = tid >> 6, lane = tid & 63;
  int k = blk * 4 + w;
  size_t row = (size_t)k * 1024;
  float f[16];
  load8(Wf, row + lane * 8, dtf, f);
  load8(Wf, row + 512 + lane * 8, dtf, f + 8);
  float acc[8];
#pragma unroll
  for (int b = 0; b < 8; ++b) {
    const float* tb = shm + b * 1024;
    float d = 0.f;
#pragma unroll
    for (int j = 0; j < 8; ++j) d += f[j]     * tb[lane * 8 + j];
#pragma unroll
    for (int j = 0; j < 8; ++j) d += f[8 + j] * tb[512 + lane * 8 + j];
    acc[b] = wredsum(d);
  }
  if (lane == 0) {
#pragma unroll
    for (int b = 0; b < 8; ++b) g_v[b * 1024 + k] = acc[b];
  }
  __syncthreads();
}

// delta[b,n] = feat[b,n,:].v ; s[b,k] += c[n]*feat[b,n,k]   (all 512 blocks)
// r5's proven low-register body: immediate per-row wredsum, c reloaded per row.
__device__ __forceinline__ void ph_feat(int blk, const void* feat, int need_delta,
                                        float* shm)
{
  int tid = threadIdx.x, w = tid >> 6, lane = tid & 63;
  int b = blk >> 6, ch = blk & 63;
  int dtf = g_dt[1];
  float vr[16];
#pragma unroll
  for (int j = 0; j < 16; ++j) vr[j] = 0.f;
  if (need_delta) {
    const float* vb = g_v + b * 1024;
#pragma unroll
    for (int j = 0; j < 8; ++j) { vr[j] = vb[lane * 8 + j]; vr[8 + j] = vb[512 + lane * 8 + j]; }
  }
  float acc[16];
#pragma unroll
  for (int j = 0; j < 16; ++j) acc[j] = 0.f;
  int n0 = ch * 64 + w * 16;
  for (int r = 0; r < 16; ++r) {
    int n = n0 + r;
    size_t row = ((size_t)b * 4096 + n) * 1024;
    float f[16];
    load8(feat, row + lane * 8, dtf, f);
    load8(feat, row + 512 + lane * 8, dtf, f + 8);
    float cn = g_c[b * 4096 + n];
#pragma unroll
    for (int j = 0; j < 16; ++j) acc[j] += cn * f[j];
    if (need_delta) {
      float dot = 0.f;
#pragma unroll
      for (int j = 0; j < 16; ++j) dot += f[j] * vr[j];
      dot = wredsum(dot);
      if (lane == 0) g_delta[b * 4096 + n] = dot;
    }
  }
#pragma unroll
  for (int j = 0; j < 8; ++j) {
    shm[w * 1024 + lane * 8 + j] = acc[j];
    shm[w * 1024 + 512 + lane * 8 + j] = acc[8 + j];
  }
  __syncthreads();
#pragma unroll
  for (int j = 0; j < 4; ++j) {
    int k = tid * 4 + j;
    float val = shm[k] + shm[1024 + k] + shm[2048 + k] + shm[3072 + k];
    atomicAdd(&g_s[b * 1024 + k], val);
  }
  __syncthreads();
}

// delta row stats -> bst update   (one b per block)
__device__ __forceinline__ void ph_stats(int b, float* sm)
{
  int tid = threadIdx.x;
  const float* row = g_delta + b * 4096;
  float xs[16], sum = 0.f, sq = 0.f;
#pragma unroll
  for (int r = 0; r < 16; ++r) { float x = row[tid + 256 * r]; xs[r] = x; sum += x; sq += x * x; }
  sm[tid] = sum; __syncthreads();
  for (int s2 = 128; s2; s2 >>= 1) { if (tid < s2) sm[tid] += sm[tid + s2]; __syncthreads(); }
  sum = sm[0]; __syncthreads();
  sm[tid] = sq; __syncthreads();
  for (int s2 = 128; s2; s2 >>= 1) { if (tid < s2) sm[tid] += sm[tid + s2]; __syncthreads(); }
  sq = sm[0];
  float mean = sum / 4096.f;
  float var = fmaxf((sq - 4096.f * mean * mean) / 4095.f, 0.f);  // ddof=1
  float inv = 1.f / (sqrtf(var) + 1e-9f);
#pragma unroll
  for (int r = 0; r < 16; ++r) {
    int i = tid + 256 * r;
    g_bst[b * 4096 + i] += (xs[r] - mean) * inv;
  }
  __syncthreads();
}

// u[b,j] += sum_{k in 16-chunk} s[b,k] * Wf[k,j]   (256 blocks: 4 jt x 64 kc)
__device__ __forceinline__ void ph_u(int blk2, const void* Wf, float* shm)
{
  int tid = threadIdx.x;
  int dtf = g_dt[3];
  int jt = blk2 & 3, kc4 = blk2 >> 2;
  if (tid < 128) {
    int b = tid >> 4, kk = tid & 15;
    shm[tid] = g_s[b * 1024 + kc4 * 16 + kk];
  }
  __syncthreads();
  int j = jt * 256 + tid;
  float acc[8] = {0,0,0,0,0,0,0,0};
  for (int kk = 0; kk < 16; ++kk) {
    int k = kc4 * 16 + kk;
    float w = ldf(Wf, (size_t)k * 1024 + j, dtf);
#pragma unroll
    for (int b = 0; b < 8; ++b) acc[b] += shm[(b << 4) + kk] * w;
  }
#pragma unroll
  for (int b = 0; b < 8; ++b) atomicAdd(&g_u[b * 1024 + j], acc[b]);
  __syncthreads();
}

// out[b,d] = u[b,:] . M[d,:]   (256 blocks, wave per d row)
__device__ __forceinline__ void ph_out(int blk, float* shm)
{
  int tid = threadIdx.x;
  for (int i = tid; i < 8192; i += 256) shm[i] = g_u[i];
  __syncthreads();
  int w = tid >> 6, lane = tid & 63;
  int d = blk * 4 + w;
  const float* row = g_M + (size_t)d * 1024;
  float f[16];
#pragma unroll
  for (int cc = 0; cc < 4; ++cc) {
    float4 x = *(const float4*)(row + cc * 256 + lane * 4);
    f[cc*4+0]=x.x; f[cc*4+1]=x.y; f[cc*4+2]=x.z; f[cc*4+3]=x.w;
  }
  float acc[8];
#pragma unroll
  for (int b = 0; b < 8; ++b) {
    const float* ub = shm + b * 1024;
    float dd = 0.f;
#pragma unroll
    for (int cc = 0; cc < 4; ++cc)
#pragma unroll
      for (int e = 0; e < 4; ++e) dd += f[cc * 4 + e] * ub[cc * 256 + lane * 4 + e];
    acc[b] = wredsum(dd);
  }
  if (lane == 0) {
#pragma unroll
    for (int b = 0; b < 8; ++b) g_outv[b * 1024 + d] = acc[b];
  }
  __syncthreads();
}

// final projection: out = qc @ Wout^T + bout   (256 blocks, wave per o row)
__device__ __forceinline__ void ph_fin(int blk, const void* Wout, const void* bout,
                                       float* __restrict__ out, float* shm)
{
  int tid = threadIdx.x;
  int dto = g_dt[7], dtb = g_dt[8];
  for (int i = tid; i < 8192; i += 256) shm[i] = g_qc[i];
  __syncthreads();
  int w = tid >> 6, lane = tid & 63;
  int o = blk * 4 + w;
  size_t row = (size_t)o * 1024;
  float f[16];
  load8(Wout, row + lane * 8, dto, f);
  load8(Wout, row + 512 + lane * 8, dto, f + 8);
  float acc[8];
#pragma unroll
  for (int b = 0; b < 8; ++b) {
    const float* qb = shm + b * 1024;
    float d = 0.f;
#pragma unroll
    for (int j = 0; j < 8; ++j) d += f[j]     * qb[lane * 8 + j];
#pragma unroll
    for (int j = 0; j < 8; ++j) d += f[8 + j] * qb[512 + lane * 8 + j];
    acc[b] = wredsum(d);
  }
  if (lane == 0) {
    float bo = ldf(bout, o, dtb);
#pragma unroll
    for (int b = 0; b < 8; ++b) out[b * 1024 + o] = acc[b] + bo;
  }
}

// ---- persistent cooperative kernel: 3 iterations + final --------------------
__global__ void __launch_bounds__(256, 2)
kcoop(const void* __restrict__ feat, const void* __restrict__ Wf,
      const void* __restrict__ lnw, const void* __restrict__ lnb,
      const void* __restrict__ Wout, const void* __restrict__ bout,
      float* __restrict__ out)
{
  cg::grid_group grid = cg::this_grid();
  __shared__ float shm[8192];                    // 32 KiB, reused per phase
  int blk = blockIdx.x;

  for (int i = 0; i < 3; ++i) {
    int nl = (i < 2);
    ph_A(blk, i, lnw, lnb, shm);                 // softmax | LN | zero s,t,u
    grid.sync();
    if (nl) {
      if (blk < 256) ph_t(blk, shm);             // t = qc @ M
      grid.sync();
      if (blk < 256) ph_v(blk, Wf, shm);         // v = t @ Wf^T
      grid.sync();
    }
    ph_feat(blk, feat, nl, shm);                 // delta + s over feat
    grid.sync();
    if (nl && blk < 8) ph_stats(blk, shm);       // delta stats -> bst
    else if (blk >= 8 && blk < 264) ph_u(blk - 8, Wf, shm);  // u = s @ Wf
    grid.sync();
    if (blk < 256) ph_out(blk, shm);             // out = u @ M^T
    grid.sync();
  }
  if (blk < 8) ph_ln(blk, g_qc, 1.f, lnw, lnb, shm);  // final LN (scale 1)
  grid.sync();
  if (blk < 256) ph_fin(blk, Wout, bout, out, shm);
}

// ---- discrete fallback wrappers (used only if cooperative launch errors) ----
__global__ void __launch_bounds__(256) fA(const void* lnw, const void* lnb, int iter)
{ __shared__ float shm[1024]; ph_A(blockIdx.x, iter, lnw, lnb, shm); }
__global__ void __launch_bounds__(256) fB()
{ __shared__ float shm[128]; ph_t(blockIdx.x, shm); }
__global__ void __launch_bounds__(256) fC(const void* Wf)
{ __shared__ float shm[8192]; ph_v(blockIdx.x, Wf, shm); }
__global__ void __launch_bounds__(256) fD(const void* feat, int nd)
{ __shared__ float shm[4096]; ph_feat(blockIdx.x, feat, nd, shm); }
__global__ void __launch_bounds__(256) fE(const void* Wf, int nl)
{
  __shared__ float shm[256];
  if (nl && blockIdx.x < 8) ph_stats(blockIdx.x, shm);
  else if (blockIdx.x >= 8 && blockIdx.x < 264) ph_u(blockIdx.x - 8, Wf, shm);
}
__global__ void __launch_bounds__(256) fF()
{ __shared__ float shm[8192]; ph_out(blockIdx.x, shm); }
__global__ void __launch_bounds__(256) fG(const void* lnw, const void* lnb)
{ __shared__ float shm[256]; ph_ln(blockIdx.x, g_qc, 1.f, lnw, lnb, shm); }
__global__ void __launch_bounds__(256) fH(const void* Wout, const void* bout, float* out)
{ __shared__ float shm[8192]; ph_fin(blockIdx.x, Wout, bout, out, shm); }

extern "C" void kernel_launch(void* const* d_in, const int* in_sizes, int n_in,
                              void* d_out, int out_size, void* d_ws, size_t ws_size,
                              hipStream_t stream)
{
  const void* query = d_in[0];
  const void* feat  = d_in[1];
  const void* Wh    = d_in[2];
  const void* Wf    = d_in[3];
  const void* Wg    = d_in[4];
  const void* lnw   = d_in[5];
  const void* lnb   = d_in[6];
  const void* Wout  = d_in[7];
  const void* bout  = d_in[8];
  const u8*   maskp = (const u8*)d_in[9];
  float* outp = (float*)d_out;
  (void)in_sizes; (void)n_in; (void)out_size; (void)d_ws; (void)ws_size;

  kdet<<<1, 640, 0, stream>>>(query, feat, Wh, Wf, Wg, lnw, lnb, Wout, bout, maskp);
  kprep<<<1120, 256, 0, stream>>>(Wg, Wh, query, maskp);

  void* args[] = {(void*)&feat, (void*)&Wf, (void*)&lnw, (void*)&lnb,
                  (void*)&Wout, (void*)&bout, (void*)&outp};
  hipError_t ce = hipLaunchCooperativeKernel((void*)kcoop, dim3(NBLK), dim3(256),
                                             args, 0, stream);
  if (ce != hipSuccess) {
    // discrete fallback: same phases as separate kernels (r5-equivalent perf)
    for (int i = 0; i < 3; ++i) {
      int nl = (i < 2);
      fA<<<40, 256, 0, stream>>>(lnw, lnb, i);
      if (nl) {
        fB<<<256, 256, 0, stream>>>();
        fC<<<256, 256, 0, stream>>>(Wf);
      }
      fD<<<512, 256, 0, stream>>>(feat, nl);
      fE<<<264, 256, 0, stream>>>(Wf, nl);
      fF<<<256, 256, 0, stream>>>();
    }
    fG<<<8, 256, 0, stream>>>(lnw, lnb);
    fH<<<256, 256, 0, stream>>>(Wout, bout, outp);
  }
}

// Round 5
// 421.792 us; speedup vs baseline: 3.1900x; 3.1900x over previous
//
#include <hip/hip_runtime.h>
#include <hip/hip_bf16.h>

// B=8, N=4096, D=1024, 3 iterations.
// r10: discrete kernels (r5 structure, proven bodies), launch count 24 -> 16.
// r8/r9 lesson: grid-wide sync in one kernel costs ~55us/sync on MI355X
// (cross-XCD coherence flushes) — persistent kernels are a dead end here.
// r6/r7 lesson: the Q=Wf@M^T precompute (2.1 GFLOP GEMM) is a bad trade.
// Algebra (r5): t = qc@M ; v = t@Wf^T ; delta[b,n] = feat[b,n,:].v
//               s = c@feat ; u = s@Wf ; out = u@M^T
// Merges in this round (all data-independent or redundant-recompute):
//   - c0 computed directly from mask inside kprep (== softmax of 0/-1e18 row)
//   - q-LN folded redundantly into the t-kernel (build_ql per block, r6-proven)
//   - next softmax + t/s zeroing ride on the out-kernel; u-zero on kt/kfeat
//   - kfin does double build_ql (LN2 then LN3) using outv kept in 2 buffers
// Launches: kdet, kprep, [kt,kv,kfd,ksu,kout]x2, kfd,ksu,kout, kfin = 16.
// Harness poisons a 512 MiB workspace (~78 us/call, fillBufferAligned) —
// unavoidable kernel-side.

using u16 = unsigned short;
using u32 = unsigned int;
using u8  = unsigned char;
using u64 = unsigned long long;

#define SELU_L 1.0507009873554805f
#define SELU_A 1.6732632423543772f

__device__ float g_M[1048576];   // Wg mean (fp32), [d][j]
__device__ float g_q[8192];      // q0 (zeroed by kdet, filled via kprep atomics)
__device__ float g_qc[8192];     // persisted LN'd q state (written by kt blk 0)
__device__ float g_t[8192];      // t = qc @ M
__device__ float g_u[8192];      // u = s @ Wf
__device__ float g_s[8192];      // s = c @ feat
__device__ float g_bst[32768];   // b logits state
__device__ float g_c[32768];     // softmax
__device__ float g_delta[32768];
__device__ float g_outv[8192];   // out of iters 0,1
__device__ float g_outv2[8192];  // out of iter 2 (kept separate for kfin)
__device__ float g_v[8192];
__device__ int   g_dt[12];       // 0..8: 0=bf16,1=f32 per float input; [9]=mask mode

__device__ __forceinline__ float blo(u32 u){ return __uint_as_float(u << 16); }
__device__ __forceinline__ float bhi(u32 u){ return __uint_as_float(u & 0xffff0000u); }
__device__ __forceinline__ float b2f(u16 u){ return __uint_as_float(((u32)u) << 16); }

__device__ __forceinline__ void unpack8(uint4 x, float* f){
  f[0]=blo(x.x); f[1]=bhi(x.x); f[2]=blo(x.y); f[3]=bhi(x.y);
  f[4]=blo(x.z); f[5]=bhi(x.z); f[6]=blo(x.w); f[7]=bhi(x.w);
}

__device__ __forceinline__ float ldf(const void* p, size_t i, int dt){
  return dt ? ((const float*)p)[i] : b2f(((const u16*)p)[i]);
}
__device__ __forceinline__ void load8(const void* base, size_t idx, int dt, float* f){
  if (dt == 0) {
    uint4 x = *(const uint4*)((const u16*)base + idx);
    unpack8(x, f);
  } else {
    const float* p = (const float*)base + idx;
    float4 a = *(const float4*)p, b = *(const float4*)(p + 4);
    f[0]=a.x; f[1]=a.y; f[2]=a.z; f[3]=a.w; f[4]=b.x; f[5]=b.y; f[6]=b.z; f[7]=b.w;
  }
}

__device__ __forceinline__ float wredsum(float x){
#pragma unroll
  for (int o = 32; o; o >>= 1) x += __shfl_xor(x, o, 64);
  return x;
}

__device__ __forceinline__ bool mon(const u8* maskp, int e, int mode){
  if (mode == 0) return maskp[e] != 0;
  if (mode == 1) return ((const int*)maskp)[e] != 0;
  if (mode == 2 || mode == 4) return ((const u16*)maskp)[e] != 0;
  if (mode == 3) return ((const u32*)maskp)[e] != 0;
  return ((const u64*)maskp)[e] != 0ULL;
}

// ---- dtype sniffer (wave-parallel) + zero q,t,u,s ---------------------------
__global__ void kdet(const void* p0, const void* p1, const void* p2, const void* p3,
                     const void* p4, const void* p5, const void* p6, const void* p7,
                     const void* p8, const void* p9)
{
  const void* ps[10] = {p0,p1,p2,p3,p4,p5,p6,p7,p8,p9};
  int tid = threadIdx.x;
  int w = tid >> 6, lane = tid & 63;
  if (w < 9) {
    const u16* wp = (const u16*)ps[w];
    u16 x0 = wp[lane], x1 = wp[64 + lane];
    int e0 = (x0 >> 7) & 0xFF, e1 = (x1 >> 7) & 0xFF;
    u64 nz0 = __ballot(x0 != 0), nz1 = __ballot(x1 != 0);
    u64 pa0 = __ballot(x0 != 0 && e0 >= 0x70 && e0 <= 0x8F);
    u64 pa1 = __ballot(x1 != 0 && e1 >= 0x70 && e1 <= 0x8F);
    if (lane == 0) {
      const u64 evenm = 0x5555555555555555ULL;   // i parity == lane parity
      int nz = __popcll(nz0) + __popcll(nz1);
      int pass = __popcll(pa0) + __popcll(pa1);
      int evenNZ = __popcll(nz0 & evenm) + __popcll(nz1 & evenm);
      int oddNZ  = nz - evenNZ;
      int dt;
      if (nz == 0)                    dt = 0;
      else if (evenNZ == 0 && oddNZ)  dt = 1;    // f32 signature
      else                            dt = (pass * 10 >= nz * 9) ? 0 : 1;
      g_dt[w] = dt;
    }
  } else if (w == 9) {
    const u8* mp = (const u8*)ps[9];
    u64 v = ((const u64*)mp)[lane];              // bytes lane*8 .. lane*8+7
    bool f16c=false, isF=false, nz01=false, nzNon4=false, nzM8_4=false, anynz=false;
#pragma unroll
    for (int j = 0; j < 8; ++j) {
      u8 cb = (u8)(v >> (8 * j));
      if (!cb) continue;
      int i = lane * 8 + j;
      anynz = true;
      if (cb == 0x3C && (i & 1)) f16c = true;
      if (cb == 0x3F || cb == 0x80) isF = true;
      int m = i & 3;
      if (m == 0 || m == 1) nz01 = true;
      if (m != 0) nzNon4 = true;
      if ((i & 7) == 4) nzM8_4 = true;
    }
    bool A  = __ballot(f16c)   != 0;
    bool Bf = __ballot(isF)    != 0;
    bool C  = __ballot(nz01)   != 0;
    bool Dn = __ballot(nzNon4) != 0;
    bool E  = __ballot(nzM8_4) != 0;
    bool F  = __ballot(anynz)  != 0;
    if (lane == 0) {
      int mode;
      if (A)       mode = 4;                     // f16
      else if (Bf) mode = C ? 2 : 3;             // bf16 : f32
      else if (Dn) mode = 0;                     // u8
      else if (E)  mode = 1;                     // i32
      else if (F)  mode = 5;                     // i64
      else         mode = 1;
      g_dt[9] = mode;
    }
  }
  for (int i = tid; i < 8192; i += 640) {
    g_q[i] = 0.f; g_t[i] = 0.f; g_u[i] = 0.f; g_s[i] = 0.f;
  }
}

// ---- prep: M (<1024) | q0 split-64 (<1088) | bst (<1120) | c0 (<1128) -------
__global__ void __launch_bounds__(256)
kprep(const void* __restrict__ Wg, const void* __restrict__ Wh,
      const void* __restrict__ query, const u8* __restrict__ maskp)
{
  int blk = blockIdx.x, tid = threadIdx.x;
  if (blk < 1024) {
    int dtg = g_dt[4];
    int e = blk * 1024 + tid * 4;
    float a0=0.f,a1=0.f,a2=0.f,a3=0.f;
#pragma unroll
    for (int g = 0; g < 4; ++g) {
      size_t o = (size_t)g * 1048576 + e;
      a0 += ldf(Wg, o+0, dtg); a1 += ldf(Wg, o+1, dtg);
      a2 += ldf(Wg, o+2, dtg); a3 += ldf(Wg, o+3, dtg);
    }
    *(float4*)(g_M + e) = make_float4(a0*0.25f, a1*0.25f, a2*0.25f, a3*0.25f);
  } else if (blk < 1088) {
    // q0[b,k] += sum_{d in chunk} query[b,d] * Wh[d,k]; 4 k-tiles x 16 d-chunks
    int dtq = g_dt[0], dth = g_dt[2];
    __shared__ float ql[512];                    // [b][64]
    int blk2 = blk - 1024;
    int kt = blk2 & 3, dc = blk2 >> 2;
    for (int idx = tid; idx < 512; idx += 256) {
      int b = idx >> 6, d = idx & 63;
      ql[idx] = ldf(query, b * 1024 + dc * 64 + d, dtq);
    }
    __syncthreads();
    int k = kt * 256 + tid;
    float acc[8] = {0,0,0,0,0,0,0,0};
    for (int dd = 0; dd < 64; ++dd) {
      int d = dc * 64 + dd;
      float w = ldf(Wh, (size_t)d * 1024 + k, dth);
#pragma unroll
      for (int b = 0; b < 8; ++b) acc[b] += ql[(b << 6) + dd] * w;
    }
#pragma unroll
    for (int b = 0; b < 8; ++b) atomicAdd(&g_q[b * 1024 + k], acc[b]);
  } else if (blk < 1120) {
    int mode = g_dt[9];
    int e0 = (blk - 1088) * 1024 + tid * 4;
#pragma unroll
    for (int j = 0; j < 4; ++j) {
      int e = e0 + j;
      g_bst[e] = mon(maskp, e, mode) ? -1e18f : 0.f;
    }
  } else {
    // c0 directly from mask: softmax of a 0/-1e18 row == uniform over unmasked
    // (bitwise identical: sum of exact 1.0s == cnt, exp(-1e18)==0).
    __shared__ int sc[256];
    int mode = g_dt[9];
    int b = blk - 1120;
    u32 bits = 0; int cnt = 0;
#pragma unroll
    for (int r = 0; r < 16; ++r) {
      int n = tid + 256 * r;
      bool on = mon(maskp, b * 4096 + n, mode);
      if (on) bits |= (1u << r); else ++cnt;
    }
    sc[tid] = cnt; __syncthreads();
    for (int s2 = 128; s2; s2 >>= 1) { if (tid < s2) sc[tid] += sc[tid + s2]; __syncthreads(); }
    int ct = sc[0];
    float inv = 1.f / (float)(ct ? ct : 4096);
    float moff = ct ? 0.f : inv;                 // all-masked: uniform 1/4096
#pragma unroll
    for (int r = 0; r < 16; ++r) {
      int n = tid + 256 * r;
      g_c[b * 4096 + n] = ((bits >> r) & 1u) ? moff : inv;
    }
  }
}

// ---- redundant q-update into LDS: ql = LN(qsrc + selu(osrc*scale)) ----------
// Deterministic fp -> bitwise identical across blocks (r6-proven). In-place
// safe for qsrc==ql (each thread reads only the elements it later writes).
__device__ __forceinline__ void build_ql(float* ql, const float* qsrc,
                                         const float* osrc, float scale,
                                         const void* lnw, const void* lnb, int tid)
{
  int w = tid >> 6, lane = tid & 63;
  int dtw = g_dt[5], dtb = g_dt[6];
#pragma unroll
  for (int rr = 0; rr < 2; ++rr) {
    int b = w + rr * 4;
    const float* qb = qsrc + b * 1024;
    const float* ob = osrc + b * 1024;
    float x[16]; float sum = 0.f, sq = 0.f;
#pragma unroll
    for (int cc = 0; cc < 4; ++cc) {
      float4 qv = *(const float4*)(qb + cc * 256 + lane * 4);
      float4 ov = *(const float4*)(ob + cc * 256 + lane * 4);
      float q4[4] = {qv.x, qv.y, qv.z, qv.w};
      float o4[4] = {ov.x, ov.y, ov.z, ov.w};
#pragma unroll
      for (int e = 0; e < 4; ++e) {
        float o = o4[e] * scale;
        float se = (o > 0.f) ? SELU_L * o : SELU_L * SELU_A * expm1f(o);
        float val = q4[e] + se;
        x[cc * 4 + e] = val; sum += val; sq += val * val;
      }
    }
    sum = wredsum(sum); sq = wredsum(sq);
    float mean = sum * (1.f / 1024.f);
    float var = fmaxf(sq * (1.f / 1024.f) - mean * mean, 0.f);   // ddof=0
    float rstd = rsqrtf(var + 1e-5f);
#pragma unroll
    for (int cc = 0; cc < 4; ++cc)
#pragma unroll
      for (int e = 0; e < 4; ++e) {
        int d = cc * 256 + lane * 4 + e;
        ql[b * 1024 + d] = (x[cc * 4 + e] - mean) * rstd * ldf(lnw, d, dtw)
                           + ldf(lnb, d, dtb);
      }
  }
  __syncthreads();
}

// ---- kt: {redundant LN -> ql} + t = ql@M (blk<256) | zero u (256..263) ------
__global__ void __launch_bounds__(256)
kt(const void* __restrict__ lnw, const void* __restrict__ lnb, int phase)
{
  __shared__ float ql[8192];
  int blk = blockIdx.x, tid = threadIdx.x;
  if (blk >= 256) {                              // zero u for this iteration
    int b = blk - 256;
    *(float4*)(g_u + b * 1024 + tid * 4) = make_float4(0.f, 0.f, 0.f, 0.f);
    return;
  }
  if (phase == 0) {
    for (int i = tid; i < 8192; i += 256) ql[i] = g_q[i];
    __syncthreads();
  } else {
    build_ql(ql, g_qc, g_outv, 1.f / 4096.f, lnw, lnb, tid);
  }
  if (blk == 0) {                                // persist qc for next LN
    for (int i = tid; i < 8192; i += 256) g_qc[i] = ql[i];
  }
  // t-GEMV: t[b,j] += sum_{dd in 16-chunk} ql[b,dd] * M[dd,j]
  int jt = blk & 3, dc4 = blk >> 2;
  int j = jt * 256 + tid;
  float acc[8] = {0,0,0,0,0,0,0,0};
  for (int dd = 0; dd < 16; ++dd) {
    int d = dc4 * 16 + dd;
    float mv = g_M[(size_t)d * 1024 + j];
#pragma unroll
    for (int b = 0; b < 8; ++b) acc[b] += ql[(b << 10) + d] * mv;
  }
#pragma unroll
  for (int b = 0; b < 8; ++b) atomicAdd(&g_t[b * 1024 + j], acc[b]);
}

// ---- kv: v[b,k] = t[b,:] . Wf[k,:]  (256 blocks, wave per k row) ------------
__global__ void __launch_bounds__(256) kv(const void* __restrict__ Wf)
{
  __shared__ float shm[8192];
  int tid = threadIdx.x;
  int dtf = g_dt[3];
  for (int i = tid; i < 8192; i += 256) shm[i] = g_t[i];
  __syncthreads();
  int w = tid >> 6, lane = tid & 63;
  int k = blockIdx.x * 4 + w;
  size_t row = (size_t)k * 1024;
  float f[16];
  load8(Wf, row + lane * 8, dtf, f);
  load8(Wf, row + 512 + lane * 8, dtf, f + 8);
  float acc[8];
#pragma unroll
  for (int b = 0; b < 8; ++b) {
    const float* tb = shm + b * 1024;
    float d = 0.f;
#pragma unroll
    for (int j = 0; j < 8; ++j) d += f[j]     * tb[lane * 8 + j];
#pragma unroll
    for (int j = 0; j < 8; ++j) d += f[8 + j] * tb[512 + lane * 8 + j];
    acc[b] = wredsum(d);
  }
  if (lane == 0) {
#pragma unroll
    for (int b = 0; b < 8; ++b) g_v[b * 1024 + k] = acc[b];
  }
}

// ---- kfd: feat pass (blk<512) | zero u (512..519, last iter only) -----------
__global__ void __launch_bounds__(256)
kfd(const void* __restrict__ feat, int need_delta)
{
  __shared__ float sl[4][1024];
  int blkx = blockIdx.x, tid = threadIdx.x;
  if (blkx >= 512) {
    int b = blkx - 512;
    *(float4*)(g_u + b * 1024 + tid * 4) = make_float4(0.f, 0.f, 0.f, 0.f);
    return;
  }
  int w = tid >> 6, lane = tid & 63;
  int b = blkx >> 6, ch = blkx & 63;
  int dtf = g_dt[1];
  float vr[16];
#pragma unroll
  for (int j = 0; j < 16; ++j) vr[j] = 0.f;
  if (need_delta) {
    const float* vb = g_v + b * 1024;
#pragma unroll
    for (int j = 0; j < 8; ++j) { vr[j] = vb[lane * 8 + j]; vr[8 + j] = vb[512 + lane * 8 + j]; }
  }
  float acc[16];
#pragma unroll
  for (int j = 0; j < 16; ++j) acc[j] = 0.f;
  int n0 = ch * 64 + w * 16;
  for (int r = 0; r < 16; ++r) {
    int n = n0 + r;
    size_t row = ((size_t)b * 4096 + n) * 1024;
    float f[16];
    load8(feat, row + lane * 8, dtf, f);
    load8(feat, row + 512 + lane * 8, dtf, f + 8);
    float cn = g_c[b * 4096 + n];
#pragma unroll
    for (int j = 0; j < 16; ++j) acc[j] += cn * f[j];
    if (need_delta) {
      float dot = 0.f;
#pragma unroll
      for (int j = 0; j < 16; ++j) dot += f[j] * vr[j];
      dot = wredsum(dot);
      if (lane == 0) g_delta[b * 4096 + n] = dot;
    }
  }
#pragma unroll
  for (int j = 0; j < 8; ++j) {
    sl[w][lane * 8 + j] = acc[j];
    sl[w][512 + lane * 8 + j] = acc[8 + j];
  }
  __syncthreads();
#pragma unroll
  for (int j = 0; j < 4; ++j) {
    int k = tid * 4 + j;
    float val = sl[0][k] + sl[1][k] + sl[2][k] + sl[3][k];
    atomicAdd(&g_s[b * 1024 + k], val);
  }
}

// ---- ksu: delta stats (blk<8, if do_stats) | u = s @ Wf (8..263) ------------
__global__ void __launch_bounds__(256)
ksu(const void* __restrict__ Wf, int do_stats)
{
  __shared__ float sm[256];
  int blk = blockIdx.x, tid = threadIdx.x;
  if (blk < 8) {
    if (!do_stats) return;
    int b = blk;
    const float* row = g_delta + b * 4096;
    float xs[16], sum = 0.f, sq = 0.f;
#pragma unroll
    for (int r = 0; r < 16; ++r) { float x = row[tid + 256 * r]; xs[r] = x; sum += x; sq += x * x; }
    sm[tid] = sum; __syncthreads();
    for (int s2 = 128; s2; s2 >>= 1) { if (tid < s2) sm[tid] += sm[tid + s2]; __syncthreads(); }
    sum = sm[0]; __syncthreads();
    sm[tid] = sq; __syncthreads();
    for (int s2 = 128; s2; s2 >>= 1) { if (tid < s2) sm[tid] += sm[tid + s2]; __syncthreads(); }
    sq = sm[0];
    float mean = sum / 4096.f;
    float var = fmaxf((sq - 4096.f * mean * mean) / 4095.f, 0.f);  // ddof=1
    float inv = 1.f / (sqrtf(var) + 1e-9f);
#pragma unroll
    for (int r = 0; r < 16; ++r) {
      int i = tid + 256 * r;
      g_bst[b * 4096 + i] += (xs[r] - mean) * inv;
    }
    return;
  }
  int dtf = g_dt[3];
  int blk2 = blk - 8;
  int jt = blk2 & 3, kc4 = blk2 >> 2;
  if (tid < 128) {
    int b = tid >> 4, kk = tid & 15;
    sm[tid] = g_s[b * 1024 + kc4 * 16 + kk];
  }
  __syncthreads();
  int j = jt * 256 + tid;
  float acc[8] = {0,0,0,0,0,0,0,0};
  for (int kk = 0; kk < 16; ++kk) {
    int k = kc4 * 16 + kk;
    float w = ldf(Wf, (size_t)k * 1024 + j, dtf);
#pragma unroll
    for (int b = 0; b < 8; ++b) acc[b] += sm[(b << 4) + kk] * w;
  }
#pragma unroll
  for (int b = 0; b < 8; ++b) atomicAdd(&g_u[b * 1024 + j], acc[b]);
}

// ---- kout: out = u@M^T (blk<256) | next softmax (256..263) | zero t (264..271)
//            | zero s (272..279) ----------------------------------------------
__global__ void __launch_bounds__(256) kout(int dst2)
{
  __shared__ float sh[8192];
  int blk = blockIdx.x, tid = threadIdx.x;
  if (blk >= 256) {
    if (blk < 264) {                             // softmax for NEXT iteration
      int b = blk - 256;
      const float* row = g_bst + b * 4096;
      float mx = -3.4e38f;
      for (int i = tid; i < 4096; i += 256) mx = fmaxf(mx, row[i]);
      sh[tid] = mx; __syncthreads();
      for (int s2 = 128; s2; s2 >>= 1) { if (tid < s2) sh[tid] = fmaxf(sh[tid], sh[tid + s2]); __syncthreads(); }
      mx = sh[0]; __syncthreads();
      float sum = 0.f;
      for (int i = tid; i < 4096; i += 256) {
        float e = __expf(row[i] - mx);
        g_c[b * 4096 + i] = e; sum += e;
      }
      sh[tid] = sum; __syncthreads();
      for (int s2 = 128; s2; s2 >>= 1) { if (tid < s2) sh[tid] += sh[tid + s2]; __syncthreads(); }
      float inv = 1.f / sh[0];
      for (int i = tid; i < 4096; i += 256) g_c[b * 4096 + i] *= inv;
    } else if (blk < 272) {
      int b = blk - 264;
      *(float4*)(g_t + b * 1024 + tid * 4) = make_float4(0.f, 0.f, 0.f, 0.f);
    } else {
      int b = blk - 272;
      *(float4*)(g_s + b * 1024 + tid * 4) = make_float4(0.f, 0.f, 0.f, 0.f);
    }
    return;
  }
  float* dst = dst2 ? g_outv2 : g_outv;
  for (int i = tid; i < 8192; i += 256) sh[i] = g_u[i];
  __syncthreads();
  int w = tid >> 6, lane = tid & 63;
  int d = blk * 4 + w;
  const float* row = g_M + (size_t)d * 1024;
  float f[16];
#pragma unroll
  for (int cc = 0; cc < 4; ++cc) {
    float4 x = *(const float4*)(row + cc * 256 + lane * 4);
    f[cc*4+0]=x.x; f[cc*4+1]=x.y; f[cc*4+2]=x.z; f[cc*4+3]=x.w;
  }
  float acc[8];
#pragma unroll
  for (int b = 0; b < 8; ++b) {
    const float* ub = sh + b * 1024;
    float dd = 0.f;
#pragma unroll
    for (int cc = 0; cc < 4; ++cc)
#pragma unroll
      for (int e = 0; e < 4; ++e) dd += f[cc * 4 + e] * ub[cc * 256 + lane * 4 + e];
    acc[b] = wredsum(dd);
  }
  if (lane == 0) {
#pragma unroll
    for (int b = 0; b < 8; ++b) dst[b * 1024 + d] = acc[b];
  }
}

// ---- kfin: double LN (qc2 from outv1, qc3 from outv2) + q3@Wout^T + bout ----
__global__ void __launch_bounds__(256)
kfin(const void* __restrict__ Wout, const void* __restrict__ bout,
     const void* __restrict__ lnw, const void* __restrict__ lnb,
     float* __restrict__ out)
{
  __shared__ float ql[8192];
  int tid = threadIdx.x;
  build_ql(ql, g_qc, g_outv, 1.f / 4096.f, lnw, lnb, tid);   // qc2 = LN(qc1, out1/n)
  build_ql(ql, ql, g_outv2, 1.f, lnw, lnb, tid);             // qc3 = LN(qc2, out2)
  int w = tid >> 6, lane = tid & 63;
  int o = blockIdx.x * 4 + w;
  int dto = g_dt[7], dtb = g_dt[8];
  size_t row = (size_t)o * 1024;
  float f[16];
  load8(Wout, row + lane * 8, dto, f);
  load8(Wout, row + 512 + lane * 8, dto, f + 8);
  float acc[8];
#pragma unroll
  for (int b = 0; b < 8; ++b) {
    const float* qb = ql + b * 1024;
    float d = 0.f;
#pragma unroll
    for (int j = 0; j < 8; ++j) d += f[j]     * qb[lane * 8 + j];
#pragma unroll
    for (int j = 0; j < 8; ++j) d += f[8 + j] * qb[512 + lane * 8 + j];
    acc[b] = wredsum(d);
  }
  if (lane == 0) {
    float bo = ldf(bout, o, dtb);
#pragma unroll
    for (int b = 0; b < 8; ++b) out[b * 1024 + o] = acc[b] + bo;
  }
}

extern "C" void kernel_launch(void* const* d_in, const int* in_sizes, int n_in,
                              void* d_out, int out_size, void* d_ws, size_t ws_size,
                              hipStream_t stream)
{
  const void* query = d_in[0];
  const void* feat  = d_in[1];
  const void* Wh    = d_in[2];
  const void* Wf    = d_in[3];
  const void* Wg    = d_in[4];
  const void* lnw   = d_in[5];
  const void* lnb   = d_in[6];
  const void* Wout  = d_in[7];
  const void* bout  = d_in[8];
  const u8*   maskp = (const u8*)d_in[9];
  (void)in_sizes; (void)n_in; (void)out_size; (void)d_ws; (void)ws_size;

  kdet<<<1, 640, 0, stream>>>(query, feat, Wh, Wf, Wg, lnw, lnb, Wout, bout, maskp);
  kprep<<<1128, 256, 0, stream>>>(Wg, Wh, query, maskp);

  // iter 0
  kt<<<264, 256, 0, stream>>>(lnw, lnb, 0);      // q0 copy + t ; zero u
  kv<<<256, 256, 0, stream>>>(Wf);
  kfd<<<512, 256, 0, stream>>>(feat, 1);
  ksu<<<264, 256, 0, stream>>>(Wf, 1);
  kout<<<280, 256, 0, stream>>>(0);              // out0 ; softmax1 ; zero t,s
  // iter 1
  kt<<<264, 256, 0, stream>>>(lnw, lnb, 1);      // LN1 + t ; zero u
  kv<<<256, 256, 0, stream>>>(Wf);
  kfd<<<512, 256, 0, stream>>>(feat, 1);
  ksu<<<264, 256, 0, stream>>>(Wf, 1);
  kout<<<280, 256, 0, stream>>>(0);              // out1 ; softmax2 ; zero t,s
  // iter 2 (last: no delta/t/v, out -> g_outv2)
  kfd<<<520, 256, 0, stream>>>(feat, 0);         // s only ; zero u (extra blks)
  ksu<<<264, 256, 0, stream>>>(Wf, 0);           // u only
  kout<<<256, 256, 0, stream>>>(1);              // out2 -> g_outv2
  kfin<<<256, 256, 0, stream>>>(Wout, bout, lnw, lnb, (float*)d_out);
}